// Round 2
// baseline (205.176 us; speedup 1.0000x reference)
//
#include <hip/hip_runtime.h>
#include <cstdint>
#include <cstddef>

// Problem shape (fixed by the reference setup_inputs)
#define MDIM 8192
#define KDIM 2048
#define NDIM 2048
#define QBLK 128
#define KB   (KDIM / QBLK)   // 16
#define NB   (NDIM / QBLK)   // 16

typedef _Float16 half8  __attribute__((ext_vector_type(8)));
typedef _Float16 half4v __attribute__((ext_vector_type(4)));
typedef float    floatx4 __attribute__((ext_vector_type(4)));

// ---------------------------------------------------------------------------
// Software fp8 e4m3fn round-to-nearest-even of q (|q| <= 448 guaranteed:
// q = x/scale with scale = max(amax,eps)/448). Returns the rounded value as f32.
// ---------------------------------------------------------------------------
__device__ inline float e4m3_rne(float q) {
    float aq = fabsf(q);
    float r;
    if (aq < 0.015625f) {                       // < 2^-6: fp8 subnormal, grid 2^-9
        r = rintf(aq * 512.0f) * 0.001953125f;  // RNE to multiple of 1/512
    } else {                                     // normal: keep 3 mantissa bits, RNE
        unsigned u = __float_as_uint(aq);
        unsigned rem = u & 0xFFFFFu;             // low 20 mantissa bits
        unsigned base = u & ~0xFFFFFu;
        unsigned inc = (rem > 0x80000u || (rem == 0x80000u && (u & 0x100000u))) ? 0x100000u : 0u;
        r = __uint_as_float(base + inc);         // carry into exp ok; 448 is on-grid
    }
    return q < 0.0f ? -r : r;
}

// Software fp8 e4m3fn decode of a raw byte.
__device__ inline float e4m3_decode(unsigned b) {
    unsigned s = b >> 7, e = (b >> 3) & 0xFu, m = b & 7u;
    float v;
    if (e == 0) v = (float)m * 0.001953125f;                       // m * 2^-9
    else        v = __uint_as_float((e + 120u) << 23) * (float)(8 + m) * 0.125f; // (1+m/8)*2^(e-7)
    return s ? -v : v;
}

// ---------------------------------------------------------------------------
// Probe: classify how the harness delivered the fp8 weight tensor.
// flag = 2: float32 upcast (byte(4i+3) = sign/exp pattern AND byte(4i+1) == 0,
//           since fp8-exact values have zero low mantissa bytes)
// flag = 1: bf16 upcast  (sign/exp pattern at byte(4i+3), byte(4i+1) nonzero pattern)
// flag = 0: raw fp8 bytes (neither)
// fp8-e4m3fn magnitudes lie in {0} U [2^-9, 448] -> f32/bf16 exp byte (sign
// stripped) in [0x3B, 0x43], or 0x00 for zero.
// ---------------------------------------------------------------------------
__device__ inline int is_expbyte(unsigned char hb) {
    unsigned char e = hb & 0x7Fu;
    return (e >= 0x3Bu && e <= 0x43u) || e == 0x00u;
}

__global__ void probe_wdtype_kernel(const unsigned char* __restrict__ wq,
                                    int* __restrict__ flag) {
    if (threadIdx.x == 0 && blockIdx.x == 0) {
        int hits3 = 0, zeros1 = 0;
        for (int i = 0; i < 64; ++i) {
            if (is_expbyte(wq[i * 4 + 3])) ++hits3;
            if (wq[i * 4 + 1] == 0) ++zeros1;
        }
        int f;
        if (hits3 >= 56) f = (zeros1 >= 56) ? 2 : 1;
        else f = 0;
        *flag = f;
    }
}

// ---------------------------------------------------------------------------
// Kernel 1: activation blockwise quant + dequant -> fp16
// Matches reference: amax over (1,128) block, scale=max(amax,1e-12)/448,
// q = e4m3fn_rne(x/scale), xdeq = q*scale, store as fp16.
// One 32-lane group per 128-elem block; 8 blocks per 256-thread workgroup.
// ---------------------------------------------------------------------------
__global__ __launch_bounds__(256) void quant_x_kernel(const float* __restrict__ x,
                                                      _Float16* __restrict__ xh) {
    const int tid = threadIdx.x;
    const int g = tid >> 5;
    const int l = tid & 31;
    const size_t bi = (size_t)blockIdx.x * 8 + g;   // block index = m*KB + kb
    const size_t base = bi << 7;

    const float4 v = *(const float4*)(x + base + (size_t)l * 4);
    float a = fmaxf(fmaxf(fabsf(v.x), fabsf(v.y)), fmaxf(fabsf(v.z), fabsf(v.w)));
    // max over 32-lane group (xor masks <32 stay within aligned 32-lane halves)
    a = fmaxf(a, __shfl_xor(a, 1));
    a = fmaxf(a, __shfl_xor(a, 2));
    a = fmaxf(a, __shfl_xor(a, 4));
    a = fmaxf(a, __shfl_xor(a, 8));
    a = fmaxf(a, __shfl_xor(a, 16));

    const float scale = fmaxf(a, 1e-12f) / 448.0f;

    half4v o;
    o[0] = (_Float16)(e4m3_rne(v.x / scale) * scale);
    o[1] = (_Float16)(e4m3_rne(v.y / scale) * scale);
    o[2] = (_Float16)(e4m3_rne(v.z / scale) * scale);
    o[3] = (_Float16)(e4m3_rne(v.w / scale) * scale);
    *(half4v*)(xh + base + (size_t)l * 4) = o;
}

// ---------------------------------------------------------------------------
// Kernel 2: weight dequant (per-(128,128)-block scale) -> fp16, flag-dispatched.
// ---------------------------------------------------------------------------
__global__ __launch_bounds__(256) void dequant_w_kernel(const void* __restrict__ wq,
                                                        const float* __restrict__ ws,
                                                        _Float16* __restrict__ wh,
                                                        const int* __restrict__ flag) {
    const size_t idx = (size_t)blockIdx.x * 256 + threadIdx.x;   // N*K/8 threads
    const size_t off = idx * 8;
    const int n = (int)(off >> 11);        // /KDIM
    const int k = (int)(off & (KDIM - 1));
    const float s = ws[((n >> 7) << 4) + (k >> 7)];   // [NB][KB] row-major

    const int f = *flag;
    half8 o;
    if (f == 2) {              // float32 upcast
        const float4* p = (const float4*)((const float*)wq + off);
        const float4 a = p[0], b = p[1];
        o[0] = (_Float16)(a.x * s); o[1] = (_Float16)(a.y * s);
        o[2] = (_Float16)(a.z * s); o[3] = (_Float16)(a.w * s);
        o[4] = (_Float16)(b.x * s); o[5] = (_Float16)(b.y * s);
        o[6] = (_Float16)(b.z * s); o[7] = (_Float16)(b.w * s);
    } else if (f == 1) {       // bf16 upcast
        const ushort4 h0 = *(const ushort4*)((const unsigned short*)wq + off);
        const ushort4 h1 = *(((const ushort4*)((const unsigned short*)wq + off)) + 1);
        o[0] = (_Float16)(__uint_as_float((unsigned)h0.x << 16) * s);
        o[1] = (_Float16)(__uint_as_float((unsigned)h0.y << 16) * s);
        o[2] = (_Float16)(__uint_as_float((unsigned)h0.z << 16) * s);
        o[3] = (_Float16)(__uint_as_float((unsigned)h0.w << 16) * s);
        o[4] = (_Float16)(__uint_as_float((unsigned)h1.x << 16) * s);
        o[5] = (_Float16)(__uint_as_float((unsigned)h1.y << 16) * s);
        o[6] = (_Float16)(__uint_as_float((unsigned)h1.z << 16) * s);
        o[7] = (_Float16)(__uint_as_float((unsigned)h1.w << 16) * s);
    } else {                   // raw fp8 bytes
        const uint2 d = *(const uint2*)((const unsigned char*)wq + off);
        o[0] = (_Float16)(e4m3_decode(d.x & 0xFF) * s);
        o[1] = (_Float16)(e4m3_decode((d.x >> 8) & 0xFF) * s);
        o[2] = (_Float16)(e4m3_decode((d.x >> 16) & 0xFF) * s);
        o[3] = (_Float16)(e4m3_decode((d.x >> 24) & 0xFF) * s);
        o[4] = (_Float16)(e4m3_decode(d.y & 0xFF) * s);
        o[5] = (_Float16)(e4m3_decode((d.y >> 8) & 0xFF) * s);
        o[6] = (_Float16)(e4m3_decode((d.y >> 16) & 0xFF) * s);
        o[7] = (_Float16)(e4m3_decode((d.y >> 24) & 0xFF) * s);
    }
    *(half8*)(wh + off) = o;
}

// ---------------------------------------------------------------------------
// Kernel 3: C[M,N] = A[M,K] * B[N,K]^T, fp16 inputs, fp32 out.
// m97 structure: 128x128 tile, BK=64, 4 waves (2x2 of 64x64), global_load_lds
// width-16 staging, mfma_f32_16x16x32_f16.
// LDS layout: row-major [128][64] halfs (128 B/row = 8 chunks of 16 B), chunk
// index XOR-swizzled by (row&7) -> conflict-free ds_read_b128 fragment reads.
// Swizzle applied on the GLOBAL side of staging (per-lane global addresses are
// free; global_load_lds LDS side must stay linear in lane).
// ---------------------------------------------------------------------------
#define BM 128
#define BN 128
#define BK 64

__global__ __launch_bounds__(256, 2) void gemm_xw_kernel(const _Float16* __restrict__ A,
                                                         const _Float16* __restrict__ B,
                                                         float* __restrict__ C) {
    __shared__ _Float16 sA[BM * BK];
    __shared__ _Float16 sB[BN * BK];
    char* sAb = (char*)sA;
    char* sBb = (char*)sB;

    const int tid  = threadIdx.x;
    const int wave = tid >> 6;
    const int lane = tid & 63;
    const int lrow = lane & 15;
    const int lk   = lane >> 4;            // 0..3
    const int wm   = (wave & 1) * 64;
    const int wn   = (wave >> 1) * 64;
    const int m0   = blockIdx.y * BM;
    const int n0   = blockIdx.x * BN;

    // staging: thread t covers LDS bytes [t*16 + it*4096, +16)
    //   -> row = t/8 + it*32, lds chunk = t&7; stored global chunk = (t&7) ^ (row&7)
    const int srow = tid >> 3;                       // 0..31
    const int gck  = (tid & 7) ^ (srow & 7);         // swizzled global 16B-chunk
    const char* agp = (const char*)(A + (size_t)(m0 + srow) * KDIM + gck * 8);
    const char* bgp = (const char*)(B + (size_t)(n0 + srow) * KDIM + gck * 8);
    const int ldsbase = tid * 16;

    floatx4 acc[4][4] = {};

    for (int kt = 0; kt < KDIM / BK; ++kt) {
        const size_t koff = (size_t)kt * (BK * 2);   // byte offset within a row
        __syncthreads();                             // LDS reuse guard
#pragma unroll
        for (int it = 0; it < 4; ++it) {
            __builtin_amdgcn_global_load_lds(
                (const __attribute__((address_space(1))) void*)(agp + (size_t)(it * 32) * (KDIM * 2) + koff),
                (__attribute__((address_space(3))) void*)(sAb + ldsbase + it * 4096),
                16, 0, 0);
        }
#pragma unroll
        for (int it = 0; it < 4; ++it) {
            __builtin_amdgcn_global_load_lds(
                (const __attribute__((address_space(1))) void*)(bgp + (size_t)(it * 32) * (KDIM * 2) + koff),
                (__attribute__((address_space(3))) void*)(sBb + ldsbase + it * 4096),
                16, 0, 0);
        }
        __syncthreads();   // implies s_waitcnt vmcnt(0) -> staging complete

#pragma unroll
        for (int ks = 0; ks < 2; ++ks) {
            half8 af[4], bf[4];
            const int ca = ((ks * 4 + lk) ^ (lrow & 7)) * 16;   // swizzled chunk byte
#pragma unroll
            for (int i = 0; i < 4; ++i) {
                const int Ra = wm + i * 16 + lrow;
                af[i] = *(const half8*)(sAb + Ra * 128 + ca);
                const int Rb = wn + i * 16 + lrow;
                bf[i] = *(const half8*)(sBb + Rb * 128 + ca);
            }
#pragma unroll
            for (int i = 0; i < 4; ++i)
#pragma unroll
                for (int j = 0; j < 4; ++j)
                    acc[i][j] = __builtin_amdgcn_mfma_f32_16x16x32_f16(af[i], bf[j], acc[i][j], 0, 0, 0);
        }
    }

    // Epilogue. C/D layout (16x16x32): col = lane&15, row = (lane>>4)*4 + reg.
#pragma unroll
    for (int i = 0; i < 4; ++i) {
        const int row0 = m0 + wm + i * 16 + lk * 4;
#pragma unroll
        for (int r = 0; r < 4; ++r) {
            float* cp = C + (size_t)(row0 + r) * NDIM + n0 + wn + lrow;
#pragma unroll
            for (int j = 0; j < 4; ++j)
                cp[j * 16] = acc[i][j][r];
        }
    }
}

// ---------------------------------------------------------------------------
extern "C" void kernel_launch(void* const* d_in, const int* in_sizes, int n_in,
                              void* d_out, int out_size, void* d_ws, size_t ws_size,
                              hipStream_t stream) {
    const float* x          = (const float*)d_in[0];
    const void* wq          = d_in[1];                 // fp8 weights, delivery fmt probed
    const float* wscale     = (const float*)d_in[2];
    float* y                = (float*)d_out;

    _Float16* xh = (_Float16*)d_ws;                                      // 32 MB
    _Float16* wh = (_Float16*)((char*)d_ws + (size_t)MDIM * KDIM * 2);   // +8 MB
    int* flag    = (int*)((char*)d_ws + (size_t)MDIM * KDIM * 2 + (size_t)NDIM * KDIM * 2);

    probe_wdtype_kernel<<<1, 64, 0, stream>>>((const unsigned char*)wq, flag);
    quant_x_kernel<<<(MDIM * KB) / 8, 256, 0, stream>>>(x, xh);
    dequant_w_kernel<<<(NDIM * KDIM / 8) / 256, 256, 0, stream>>>(wq, wscale, wh, flag);
    gemm_xw_kernel<<<dim3(NDIM / BN, MDIM / BM), 256, 0, stream>>>(xh, wh, y);
}

// Round 3
// 196.353 us; speedup vs baseline: 1.0449x; 1.0449x over previous
//
#include <hip/hip_runtime.h>
#include <cstdint>
#include <cstddef>

// Problem shape (fixed by the reference setup_inputs)
#define MDIM 8192
#define KDIM 2048
#define NDIM 2048
#define QBLK 128
#define KB   (KDIM / QBLK)   // 16
#define NB   (NDIM / QBLK)   // 16

typedef _Float16 half8  __attribute__((ext_vector_type(8)));
typedef _Float16 half4v __attribute__((ext_vector_type(4)));
typedef float    floatx4 __attribute__((ext_vector_type(4)));

// ---------------------------------------------------------------------------
// Software fp8 e4m3fn round-to-nearest-even of q (|q| <= 448 guaranteed:
// q = x/scale with scale = max(amax,eps)/448). Returns the rounded value as f32.
// ---------------------------------------------------------------------------
__device__ inline float e4m3_rne(float q) {
    float aq = fabsf(q);
    float r;
    if (aq < 0.015625f) {                       // < 2^-6: fp8 subnormal, grid 2^-9
        r = rintf(aq * 512.0f) * 0.001953125f;  // RNE to multiple of 1/512
    } else {                                     // normal: keep 3 mantissa bits, RNE
        unsigned u = __float_as_uint(aq);
        unsigned rem = u & 0xFFFFFu;             // low 20 mantissa bits
        unsigned base = u & ~0xFFFFFu;
        unsigned inc = (rem > 0x80000u || (rem == 0x80000u && (u & 0x100000u))) ? 0x100000u : 0u;
        r = __uint_as_float(base + inc);         // carry into exp ok; 448 is on-grid
    }
    return q < 0.0f ? -r : r;
}

// Software fp8 e4m3fn decode of a raw byte.
__device__ inline float e4m3_decode(unsigned b) {
    unsigned s = b >> 7, e = (b >> 3) & 0xFu, m = b & 7u;
    float v;
    if (e == 0) v = (float)m * 0.001953125f;                       // m * 2^-9
    else        v = __uint_as_float((e + 120u) << 23) * (float)(8 + m) * 0.125f; // (1+m/8)*2^(e-7)
    return s ? -v : v;
}

// Weight-delivery classifier helper: is this byte a plausible f32/bf16 high
// (sign|exponent) byte for an fp8-e4m3fn-exact magnitude ({0} U [2^-9, 448])?
__device__ inline int is_expbyte(unsigned b) {
    unsigned e = b & 0x7Fu;
    return (e >= 0x3Bu && e <= 0x43u) || e == 0x00u;
}

// ---------------------------------------------------------------------------
// Fused prep kernel.
//   blocks [0, QXB)           : activation blockwise quant+dequant -> fp16
//   blocks [QXB, QXB+DWB)     : weight dequant -> fp16, with inline per-wave
//                               dtype classification of the delivered buffer
//                               (f32-upcast / bf16-upcast / raw fp8) via
//                               ballot over the first 256 bytes.
// ---------------------------------------------------------------------------
#define QXB ((MDIM * KB) / 8)        // 16384 quant blocks (8 x 128-elem blocks each)
#define DWB ((NDIM * KDIM / 8) / 256) // 2048 dequant blocks

__global__ __launch_bounds__(256) void prep_kernel(const float* __restrict__ x,
                                                   const void* __restrict__ wq,
                                                   const float* __restrict__ ws,
                                                   _Float16* __restrict__ xh,
                                                   _Float16* __restrict__ wh) {
    const int tid = threadIdx.x;
    if (blockIdx.x < QXB) {
        // ---------------- activation quant ----------------
        const int g = tid >> 5;
        const int l = tid & 31;
        const size_t bi = (size_t)blockIdx.x * 8 + g;   // block index = m*KB + kb
        const size_t base = bi << 7;

        const float4 v = *(const float4*)(x + base + (size_t)l * 4);
        float a = fmaxf(fmaxf(fabsf(v.x), fabsf(v.y)), fmaxf(fabsf(v.z), fabsf(v.w)));
        // max over 32-lane group (xor masks <32 stay within aligned halves)
        a = fmaxf(a, __shfl_xor(a, 1));
        a = fmaxf(a, __shfl_xor(a, 2));
        a = fmaxf(a, __shfl_xor(a, 4));
        a = fmaxf(a, __shfl_xor(a, 8));
        a = fmaxf(a, __shfl_xor(a, 16));

        const float scale = fmaxf(a, 1e-12f) / 448.0f;

        half4v o;
        o[0] = (_Float16)(e4m3_rne(v.x / scale) * scale);
        o[1] = (_Float16)(e4m3_rne(v.y / scale) * scale);
        o[2] = (_Float16)(e4m3_rne(v.z / scale) * scale);
        o[3] = (_Float16)(e4m3_rne(v.w / scale) * scale);
        *(half4v*)(xh + base + (size_t)l * 4) = o;
    } else {
        // ---------------- weight dequant ----------------
        // Inline dtype classification: every wave inspects the same first 256
        // bytes of wq (L1/L2-hot after the first block) -> wave-uniform flag.
        const int lane = tid & 63;
        const unsigned pw = ((const unsigned*)wq)[lane];
        const unsigned long long m3 = __ballot(is_expbyte((pw >> 24) & 0xFFu));
        const unsigned long long m1 = __ballot(((pw >> 8) & 0xFFu) == 0u);
        const int hits3 = __popcll(m3);
        const int zeros1 = __popcll(m1);
        const int f = (hits3 >= 56) ? ((zeros1 >= 56) ? 2 : 1) : 0;

        const size_t idx = (size_t)(blockIdx.x - QXB) * 256 + tid;
        const size_t off = idx * 8;
        const int n = (int)(off >> 11);        // / KDIM
        const int k = (int)(off & (KDIM - 1));
        const float s = ws[((n >> 7) << 4) + (k >> 7)];   // [NB][KB] row-major

        half8 o;
        if (f == 2) {              // float32 upcast
            const float4* p = (const float4*)((const float*)wq + off);
            const float4 a = p[0], b = p[1];
            o[0] = (_Float16)(a.x * s); o[1] = (_Float16)(a.y * s);
            o[2] = (_Float16)(a.z * s); o[3] = (_Float16)(a.w * s);
            o[4] = (_Float16)(b.x * s); o[5] = (_Float16)(b.y * s);
            o[6] = (_Float16)(b.z * s); o[7] = (_Float16)(b.w * s);
        } else if (f == 1) {       // bf16 upcast
            const ushort4 h0 = *(const ushort4*)((const unsigned short*)wq + off);
            const ushort4 h1 = *(((const ushort4*)((const unsigned short*)wq + off)) + 1);
            o[0] = (_Float16)(__uint_as_float((unsigned)h0.x << 16) * s);
            o[1] = (_Float16)(__uint_as_float((unsigned)h0.y << 16) * s);
            o[2] = (_Float16)(__uint_as_float((unsigned)h0.z << 16) * s);
            o[3] = (_Float16)(__uint_as_float((unsigned)h0.w << 16) * s);
            o[4] = (_Float16)(__uint_as_float((unsigned)h1.x << 16) * s);
            o[5] = (_Float16)(__uint_as_float((unsigned)h1.y << 16) * s);
            o[6] = (_Float16)(__uint_as_float((unsigned)h1.z << 16) * s);
            o[7] = (_Float16)(__uint_as_float((unsigned)h1.w << 16) * s);
        } else {                   // raw fp8 bytes
            const uint2 d = *(const uint2*)((const unsigned char*)wq + off);
            o[0] = (_Float16)(e4m3_decode(d.x & 0xFF) * s);
            o[1] = (_Float16)(e4m3_decode((d.x >> 8) & 0xFF) * s);
            o[2] = (_Float16)(e4m3_decode((d.x >> 16) & 0xFF) * s);
            o[3] = (_Float16)(e4m3_decode((d.x >> 24) & 0xFF) * s);
            o[4] = (_Float16)(e4m3_decode(d.y & 0xFF) * s);
            o[5] = (_Float16)(e4m3_decode((d.y >> 8) & 0xFF) * s);
            o[6] = (_Float16)(e4m3_decode((d.y >> 16) & 0xFF) * s);
            o[7] = (_Float16)(e4m3_decode((d.y >> 24) & 0xFF) * s);
        }
        *(half8*)(wh + off) = o;
    }
}

// ---------------------------------------------------------------------------
// GEMM kernel (UNCHANGED from R2 — control): C[M,N] = A[M,K] * B[N,K]^T.
// m97 structure: 128x128 tile, BK=64, 4 waves (2x2 of 64x64), global_load_lds
// width-16 staging, mfma_f32_16x16x32_f16, XOR-swizzled LDS chunks
// (0 bank conflicts measured).
// ---------------------------------------------------------------------------
#define BM 128
#define BN 128
#define BK 64

__global__ __launch_bounds__(256, 2) void gemm_xw_kernel(const _Float16* __restrict__ A,
                                                         const _Float16* __restrict__ B,
                                                         float* __restrict__ C) {
    __shared__ _Float16 sA[BM * BK];
    __shared__ _Float16 sB[BN * BK];
    char* sAb = (char*)sA;
    char* sBb = (char*)sB;

    const int tid  = threadIdx.x;
    const int wave = tid >> 6;
    const int lane = tid & 63;
    const int lrow = lane & 15;
    const int lk   = lane >> 4;            // 0..3
    const int wm   = (wave & 1) * 64;
    const int wn   = (wave >> 1) * 64;
    const int m0   = blockIdx.y * BM;
    const int n0   = blockIdx.x * BN;

    // staging: thread t covers LDS bytes [t*16 + it*4096, +16)
    //   -> row = t/8 + it*32, lds chunk = t&7; stored global chunk = (t&7) ^ (row&7)
    const int srow = tid >> 3;                       // 0..31
    const int gck  = (tid & 7) ^ (srow & 7);         // swizzled global 16B-chunk
    const char* agp = (const char*)(A + (size_t)(m0 + srow) * KDIM + gck * 8);
    const char* bgp = (const char*)(B + (size_t)(n0 + srow) * KDIM + gck * 8);
    const int ldsbase = tid * 16;

    floatx4 acc[4][4] = {};

    for (int kt = 0; kt < KDIM / BK; ++kt) {
        const size_t koff = (size_t)kt * (BK * 2);   // byte offset within a row
        __syncthreads();                             // LDS reuse guard
#pragma unroll
        for (int it = 0; it < 4; ++it) {
            __builtin_amdgcn_global_load_lds(
                (const __attribute__((address_space(1))) void*)(agp + (size_t)(it * 32) * (KDIM * 2) + koff),
                (__attribute__((address_space(3))) void*)(sAb + ldsbase + it * 4096),
                16, 0, 0);
        }
#pragma unroll
        for (int it = 0; it < 4; ++it) {
            __builtin_amdgcn_global_load_lds(
                (const __attribute__((address_space(1))) void*)(bgp + (size_t)(it * 32) * (KDIM * 2) + koff),
                (__attribute__((address_space(3))) void*)(sBb + ldsbase + it * 4096),
                16, 0, 0);
        }
        __syncthreads();   // implies s_waitcnt vmcnt(0) -> staging complete

#pragma unroll
        for (int ks = 0; ks < 2; ++ks) {
            half8 af[4], bf[4];
            const int ca = ((ks * 4 + lk) ^ (lrow & 7)) * 16;   // swizzled chunk byte
#pragma unroll
            for (int i = 0; i < 4; ++i) {
                const int Ra = wm + i * 16 + lrow;
                af[i] = *(const half8*)(sAb + Ra * 128 + ca);
                const int Rb = wn + i * 16 + lrow;
                bf[i] = *(const half8*)(sBb + Rb * 128 + ca);
            }
#pragma unroll
            for (int i = 0; i < 4; ++i)
#pragma unroll
                for (int j = 0; j < 4; ++j)
                    acc[i][j] = __builtin_amdgcn_mfma_f32_16x16x32_f16(af[i], bf[j], acc[i][j], 0, 0, 0);
        }
    }

    // Epilogue. C/D layout (16x16x32): col = lane&15, row = (lane>>4)*4 + reg.
#pragma unroll
    for (int i = 0; i < 4; ++i) {
        const int row0 = m0 + wm + i * 16 + lk * 4;
#pragma unroll
        for (int r = 0; r < 4; ++r) {
            float* cp = C + (size_t)(row0 + r) * NDIM + n0 + wn + lrow;
#pragma unroll
            for (int j = 0; j < 4; ++j)
                cp[j * 16] = acc[i][j][r];
        }
    }
}

// ---------------------------------------------------------------------------
extern "C" void kernel_launch(void* const* d_in, const int* in_sizes, int n_in,
                              void* d_out, int out_size, void* d_ws, size_t ws_size,
                              hipStream_t stream) {
    const float* x          = (const float*)d_in[0];
    const void* wq          = d_in[1];                 // fp8 weights, delivery fmt probed inline
    const float* wscale     = (const float*)d_in[2];
    float* y                = (float*)d_out;

    _Float16* xh = (_Float16*)d_ws;                                      // 32 MB
    _Float16* wh = (_Float16*)((char*)d_ws + (size_t)MDIM * KDIM * 2);   // +8 MB

    prep_kernel<<<QXB + DWB, 256, 0, stream>>>(x, wq, wscale, xh, wh);
    gemm_xw_kernel<<<dim3(NDIM / BN, MDIM / BM), 256, 0, stream>>>(xh, wh, y);
}

// Round 4
// 184.066 us; speedup vs baseline: 1.1147x; 1.0668x over previous
//
#include <hip/hip_runtime.h>
#include <cstdint>
#include <cstddef>

// Problem shape (fixed by the reference setup_inputs)
#define MDIM 8192
#define KDIM 2048
#define NDIM 2048
#define QBLK 128
#define KB   (KDIM / QBLK)   // 16
#define NB   (NDIM / QBLK)   // 16

typedef float floatx4 __attribute__((ext_vector_type(4)));
typedef int   int4v   __attribute__((ext_vector_type(4)));
typedef int   int8v   __attribute__((ext_vector_type(8)));

#define AS1 __attribute__((address_space(1)))
#define AS3 __attribute__((address_space(3)))

// ---------------------------------------------------------------------------
// fp8 e4m3fn helpers (software, bit-exact)
// ---------------------------------------------------------------------------
__device__ inline float e4m3_rne(float q) {     // RNE to fp8 grid, |q| <= 448
    float aq = fabsf(q);
    float r;
    if (aq < 0.015625f) {                        // subnormal: grid 2^-9
        r = rintf(aq * 512.0f) * 0.001953125f;
    } else {
        unsigned u = __float_as_uint(aq);
        unsigned rem = u & 0xFFFFFu;
        unsigned base = u & ~0xFFFFFu;
        unsigned inc = (rem > 0x80000u || (rem == 0x80000u && (u & 0x100000u))) ? 0x100000u : 0u;
        r = __uint_as_float(base + inc);
    }
    return q < 0.0f ? -r : r;
}

__device__ inline unsigned e4m3_encode(float r) {  // r exactly on fp8 grid
    unsigned u = __float_as_uint(r);
    unsigned s = (u >> 24) & 0x80u;
    float a = fabsf(r);
    if (a < 0.015625f) return s | (unsigned)(a * 512.0f + 0.25f);
    unsigned e = ((u >> 23) & 0xFFu) - 120u;       // 1..15
    unsigned m = (u >> 20) & 7u;
    return s | (e << 3) | m;
}

__device__ inline float e4m3_decode(unsigned b) {
    unsigned s = b >> 7, e = (b >> 3) & 0xFu, m = b & 7u;
    float v;
    if (e == 0) v = (float)m * 0.001953125f;
    else        v = __uint_as_float((e + 120u) << 23) * (float)(8 + m) * 0.125f;
    return s ? -v : v;
}

__device__ inline int is_expbyte(unsigned b) {   // plausible f32/bf16 hi byte for fp8-exact value
    unsigned e = b & 0x7Fu;
    return (e >= 0x3Bu && e <= 0x43u) || e == 0x00u;
}

// ---------------------------------------------------------------------------
// Workspace layout
//   xq  [M][K]  fp8 bytes            @ 0        (16 MB)
//   wq8 [N][K]  fp8 bytes            @ 16 MB    (4 MB)
//   xs  [M][KB] f32 act scales       @ 20 MB    (512 KB)
//   flag int                         @ 20.5 MB
// ---------------------------------------------------------------------------
#define XQ_OFF  0
#define WQ_OFF  ((size_t)MDIM * KDIM)
#define XS_OFF  (WQ_OFF + (size_t)NDIM * KDIM)
#define FL_OFF  (XS_OFF + (size_t)MDIM * KB * 4)

#define QXB ((MDIM * KB) / 8)          // 16384 act-quant blocks
#define DWB ((NDIM * KDIM / 8) / 256)  // 2048 weight blocks

// ---------------------------------------------------------------------------
// Prep: act quant -> fp8 bytes + scales; weight -> fp8 bytes (delivery-format
// classified inline per wave via ballot over the first 256 bytes). Also zeroes
// the fallback flag.
// ---------------------------------------------------------------------------
__global__ __launch_bounds__(256) void prep_kernel(const float* __restrict__ x,
                                                   const void* __restrict__ wq,
                                                   unsigned char* __restrict__ xq,
                                                   unsigned char* __restrict__ wq8,
                                                   float* __restrict__ xs,
                                                   int* __restrict__ flag) {
    const int tid = threadIdx.x;
    if (blockIdx.x == 0 && tid == 0) *flag = 0;

    if (blockIdx.x < QXB) {
        // ---- activation quant: one 32-lane group per (1,128) block ----
        const int g = tid >> 5;
        const int l = tid & 31;
        const size_t bi = (size_t)blockIdx.x * 8 + g;    // = m*KB + kb
        const size_t base = bi << 7;

        const float4 v = *(const float4*)(x + base + (size_t)l * 4);
        float a = fmaxf(fmaxf(fabsf(v.x), fabsf(v.y)), fmaxf(fabsf(v.z), fabsf(v.w)));
        a = fmaxf(a, __shfl_xor(a, 1));
        a = fmaxf(a, __shfl_xor(a, 2));
        a = fmaxf(a, __shfl_xor(a, 4));
        a = fmaxf(a, __shfl_xor(a, 8));
        a = fmaxf(a, __shfl_xor(a, 16));

        const float scale = fmaxf(a, 1e-12f) / 448.0f;
        if (l == 0) xs[bi] = scale;

        unsigned b0 = e4m3_encode(e4m3_rne(v.x / scale));
        unsigned b1 = e4m3_encode(e4m3_rne(v.y / scale));
        unsigned b2 = e4m3_encode(e4m3_rne(v.z / scale));
        unsigned b3 = e4m3_encode(e4m3_rne(v.w / scale));
        *(unsigned*)(xq + base + (size_t)l * 4) = b0 | (b1 << 8) | (b2 << 16) | (b3 << 24);
    } else {
        // ---- weight repack to fp8 bytes ----
        const int lane = tid & 63;
        const unsigned pw = ((const unsigned*)wq)[lane];
        const unsigned long long m3 = __ballot(is_expbyte((pw >> 24) & 0xFFu));
        const unsigned long long m1 = __ballot(((pw >> 8) & 0xFFu) == 0u);
        const int f = (__popcll(m3) >= 56) ? ((__popcll(m1) >= 56) ? 2 : 1) : 0;

        const size_t idx = (size_t)(blockIdx.x - QXB) * 256 + tid;
        const size_t off = idx * 8;

        unsigned lo, hi;
        if (f == 2) {              // float32 upcast delivery
            const float4* p = (const float4*)((const float*)wq + off);
            const float4 a = p[0], b = p[1];
            lo = e4m3_encode(a.x) | (e4m3_encode(a.y) << 8) | (e4m3_encode(a.z) << 16) | (e4m3_encode(a.w) << 24);
            hi = e4m3_encode(b.x) | (e4m3_encode(b.y) << 8) | (e4m3_encode(b.z) << 16) | (e4m3_encode(b.w) << 24);
        } else if (f == 1) {       // bf16 upcast delivery
            const ushort4 h0 = *(const ushort4*)((const unsigned short*)wq + off);
            const ushort4 h1 = *(((const ushort4*)((const unsigned short*)wq + off)) + 1);
            lo = e4m3_encode(__uint_as_float((unsigned)h0.x << 16))
               | (e4m3_encode(__uint_as_float((unsigned)h0.y << 16)) << 8)
               | (e4m3_encode(__uint_as_float((unsigned)h0.z << 16)) << 16)
               | (e4m3_encode(__uint_as_float((unsigned)h0.w << 16)) << 24);
            hi = e4m3_encode(__uint_as_float((unsigned)h1.x << 16))
               | (e4m3_encode(__uint_as_float((unsigned)h1.y << 16)) << 8)
               | (e4m3_encode(__uint_as_float((unsigned)h1.z << 16)) << 16)
               | (e4m3_encode(__uint_as_float((unsigned)h1.w << 16)) << 24);
        } else {                   // already raw fp8 bytes
            const uint2 d = *(const uint2*)((const unsigned char*)wq + off);
            lo = d.x; hi = d.y;
        }
        *(uint2*)(wq8 + off) = make_uint2(lo, hi);
    }
}

// ---------------------------------------------------------------------------
// Primary GEMM: MX fp8, K=128 per MFMA (= one quant block), HW scales = 1.0,
// per-block fp32 scale applied as VALU fixup. 128x128 tile, 4 waves (2x2 of
// 64x64), global_load_lds width-16, XOR-swizzled 16B chunks (rows are 128 B =
// exactly 32 banks, so unswizzled fragment reads would be 16-way conflicted).
// A-fragment layout assumption: row = lane&15, k = (lane>>4)*32 + byte.
// ---------------------------------------------------------------------------
__global__ __launch_bounds__(256, 2) void gemm_mx_kernel(const unsigned char* __restrict__ Aq,
                                                         const unsigned char* __restrict__ Bq,
                                                         const float* __restrict__ xs,
                                                         const float* __restrict__ wsc,
                                                         float* __restrict__ C) {
    __shared__ unsigned char sA[128 * 128];   // 16 KB
    __shared__ unsigned char sB[128 * 128];   // 16 KB

    const int tid  = threadIdx.x;
    const int wave = tid >> 6;
    const int lane = tid & 63;
    const int lrow = lane & 15;
    const int lk   = lane >> 4;          // k-group (32 bytes each)
    const int wm   = (wave & 1) * 64;
    const int wn   = (wave >> 1) * 64;
    const int m0   = blockIdx.y * 128;
    const int n0   = blockIdx.x * 128;
    const int nb   = n0 >> 7;

    // staging: thread t -> LDS bytes [t*16 + it*4096): row = t/8 + it*32,
    // physical chunk = t&7 holding logical chunk (t&7)^(row&7).
    const int srow = tid >> 3;
    const int gck  = (tid & 7) ^ (srow & 7);
    const unsigned char* agp = Aq + (size_t)(m0 + srow) * KDIM + gck * 16;
    const unsigned char* bgp = Bq + (size_t)(n0 + srow) * KDIM + gck * 16;

    floatx4 acc[4][4] = {};
    const floatx4 zero = {0.f, 0.f, 0.f, 0.f};

    for (int kb = 0; kb < KB; ++kb) {            // 16 iterations, 128 K each
        const size_t koff = (size_t)kb * QBLK;   // byte offset in a row
        __syncthreads();
#pragma unroll
        for (int it = 0; it < 4; ++it)
            __builtin_amdgcn_global_load_lds(
                (const AS1 void*)(agp + (size_t)(it * 32) * KDIM + koff),
                (AS3 void*)(sA + tid * 16 + it * 4096), 16, 0, 0);
#pragma unroll
        for (int it = 0; it < 4; ++it)
            __builtin_amdgcn_global_load_lds(
                (const AS1 void*)(bgp + (size_t)(it * 32) * KDIM + koff),
                (AS3 void*)(sB + tid * 16 + it * 4096), 16, 0, 0);
        __syncthreads();

        // fragments: logical bytes [lk*32, lk*32+32) of each row
        int8v af[4], bf[4];
#pragma unroll
        for (int i = 0; i < 4; ++i) {
            const int Ra = wm + i * 16 + lrow;
            const int c0 = (lk * 2) ^ (Ra & 7);
            const int c1 = (lk * 2 + 1) ^ (Ra & 7);
            int4v alo = *(const int4v*)(sA + Ra * 128 + c0 * 16);
            int4v ahi = *(const int4v*)(sA + Ra * 128 + c1 * 16);
            af[i] = __builtin_shufflevector(alo, ahi, 0, 1, 2, 3, 4, 5, 6, 7);
            const int Rb = wn + i * 16 + lrow;
            const int d0 = (lk * 2) ^ (Rb & 7);
            const int d1 = (lk * 2 + 1) ^ (Rb & 7);
            int4v blo = *(const int4v*)(sB + Rb * 128 + d0 * 16);
            int4v bhi = *(const int4v*)(sB + Rb * 128 + d1 * 16);
            bf[i] = __builtin_shufflevector(blo, bhi, 0, 1, 2, 3, 4, 5, 6, 7);
        }

        // combined per-row scales for this k-block (C/D row = lk*4 + r)
        const float wsk = wsc[nb * KB + kb];
        float cs[4][4];
#pragma unroll
        for (int i = 0; i < 4; ++i)
#pragma unroll
            for (int r = 0; r < 4; ++r)
                cs[i][r] = xs[(size_t)(m0 + wm + i * 16 + lk * 4 + r) * KB + kb] * wsk;

#pragma unroll
        for (int i = 0; i < 4; ++i)
#pragma unroll
            for (int j = 0; j < 4; ++j) {
                floatx4 blk = __builtin_amdgcn_mfma_scale_f32_16x16x128_f8f6f4(
                    af[i], bf[j], zero, 0, 0, 0, 0x7F7F7F7F, 0, 0x7F7F7F7F);
#pragma unroll
                for (int r = 0; r < 4; ++r)
                    acc[i][j][r] += cs[i][r] * blk[r];
            }
    }

    // Epilogue: col = lane&15, row = lk*4 + r.
#pragma unroll
    for (int i = 0; i < 4; ++i) {
        const int row0 = m0 + wm + i * 16 + lk * 4;
#pragma unroll
        for (int r = 0; r < 4; ++r) {
            float* cp = C + (size_t)(row0 + r) * NDIM + n0 + wn + lrow;
#pragma unroll
            for (int j = 0; j < 4; ++j)
                cp[j * 16] = acc[i][j][r];
        }
    }
}

// ---------------------------------------------------------------------------
// Check: recompute 64 sampled outputs exactly from the quantized bytes; set
// flag if the MX GEMM result deviates (NaN-safe compare).
// ---------------------------------------------------------------------------
__global__ __launch_bounds__(256) void check_kernel(const unsigned char* __restrict__ xq,
                                                    const unsigned char* __restrict__ wq8,
                                                    const float* __restrict__ xs,
                                                    const float* __restrict__ wsc,
                                                    const float* __restrict__ y,
                                                    int* __restrict__ flag) {
    const int s = blockIdx.x;
    const int m = (s * 1237 + 11) & (MDIM - 1);
    const int n = (s * 389 + 7) & (NDIM - 1);
    const int tid = threadIdx.x;
    const int k0 = tid * 8;
    const int kb = k0 >> 7;

    const unsigned char* xp = xq + (size_t)m * KDIM + k0;
    const unsigned char* wp = wq8 + (size_t)n * KDIM + k0;
    float dot = 0.f;
#pragma unroll
    for (int i = 0; i < 8; ++i)
        dot += e4m3_decode(xp[i]) * e4m3_decode(wp[i]);
    float part = dot * xs[m * KB + kb] * wsc[(n >> 7) * KB + kb];

#pragma unroll
    for (int o = 32; o > 0; o >>= 1) part += __shfl_down(part, o);
    __shared__ float wsum[4];
    if ((tid & 63) == 0) wsum[tid >> 6] = part;
    __syncthreads();
    if (tid == 0) {
        const float tot = wsum[0] + wsum[1] + wsum[2] + wsum[3];
        const float d = tot - y[(size_t)m * NDIM + n];
        if (!(fabsf(d) <= 0.05f)) atomicOr(flag, 1);
    }
}

// ---------------------------------------------------------------------------
// Fallback GEMM (flag-guarded): non-scaled mfma_f32_16x16x32_fp8_fp8 (m145-
// verified k-geometry: k = (lane>>4)*8 + byte) + identical VALU scale fixup.
// Same staging/swizzle as gemm_mx. Only runs if the MX layout check failed.
// ---------------------------------------------------------------------------
__global__ __launch_bounds__(256, 2) void gemm_fb_kernel(const unsigned char* __restrict__ Aq,
                                                         const unsigned char* __restrict__ Bq,
                                                         const float* __restrict__ xs,
                                                         const float* __restrict__ wsc,
                                                         float* __restrict__ C,
                                                         const int* __restrict__ flag) {
    if (*flag == 0) return;

    __shared__ unsigned char sA[128 * 128];
    __shared__ unsigned char sB[128 * 128];

    const int tid  = threadIdx.x;
    const int wave = tid >> 6;
    const int lane = tid & 63;
    const int lrow = lane & 15;
    const int lk   = lane >> 4;
    const int wm   = (wave & 1) * 64;
    const int wn   = (wave >> 1) * 64;
    const int m0   = blockIdx.y * 128;
    const int n0   = blockIdx.x * 128;
    const int nb   = n0 >> 7;

    const int srow = tid >> 3;
    const int gck  = (tid & 7) ^ (srow & 7);
    const unsigned char* agp = Aq + (size_t)(m0 + srow) * KDIM + gck * 16;
    const unsigned char* bgp = Bq + (size_t)(n0 + srow) * KDIM + gck * 16;

    floatx4 acc[4][4] = {};

    for (int kb = 0; kb < KB; ++kb) {
        const size_t koff = (size_t)kb * QBLK;
        __syncthreads();
#pragma unroll
        for (int it = 0; it < 4; ++it)
            __builtin_amdgcn_global_load_lds(
                (const AS1 void*)(agp + (size_t)(it * 32) * KDIM + koff),
                (AS3 void*)(sA + tid * 16 + it * 4096), 16, 0, 0);
#pragma unroll
        for (int it = 0; it < 4; ++it)
            __builtin_amdgcn_global_load_lds(
                (const AS1 void*)(bgp + (size_t)(it * 32) * KDIM + koff),
                (AS3 void*)(sB + tid * 16 + it * 4096), 16, 0, 0);
        __syncthreads();

        floatx4 blk[4][4] = {};
#pragma unroll
        for (int ks = 0; ks < 4; ++ks) {        // K = 32 per MFMA
            long a8[4], b8[4];
            const int lc = ks * 2 + (lk >> 1);  // logical chunk of this 8B frag
            const int bo = (lk & 1) * 8;        // byte offset within chunk
#pragma unroll
            for (int i = 0; i < 4; ++i) {
                const int Ra = wm + i * 16 + lrow;
                a8[i] = *(const long*)(sA + Ra * 128 + (lc ^ (Ra & 7)) * 16 + bo);
                const int Rb = wn + i * 16 + lrow;
                b8[i] = *(const long*)(sB + Rb * 128 + (lc ^ (Rb & 7)) * 16 + bo);
            }
#pragma unroll
            for (int i = 0; i < 4; ++i)
#pragma unroll
                for (int j = 0; j < 4; ++j)
                    blk[i][j] = __builtin_amdgcn_mfma_f32_16x16x32_fp8_fp8(a8[i], b8[j], blk[i][j], 0, 0, 0);
        }

        const float wsk = wsc[nb * KB + kb];
#pragma unroll
        for (int i = 0; i < 4; ++i) {
            float cs[4];
#pragma unroll
            for (int r = 0; r < 4; ++r)
                cs[r] = xs[(size_t)(m0 + wm + i * 16 + lk * 4 + r) * KB + kb] * wsk;
#pragma unroll
            for (int j = 0; j < 4; ++j)
#pragma unroll
                for (int r = 0; r < 4; ++r)
                    acc[i][j][r] += cs[r] * blk[i][j][r];
        }
    }

#pragma unroll
    for (int i = 0; i < 4; ++i) {
        const int row0 = m0 + wm + i * 16 + lk * 4;
#pragma unroll
        for (int r = 0; r < 4; ++r) {
            float* cp = C + (size_t)(row0 + r) * NDIM + n0 + wn + lrow;
#pragma unroll
            for (int j = 0; j < 4; ++j)
                cp[j * 16] = acc[i][j][r];
        }
    }
}

// ---------------------------------------------------------------------------
extern "C" void kernel_launch(void* const* d_in, const int* in_sizes, int n_in,
                              void* d_out, int out_size, void* d_ws, size_t ws_size,
                              hipStream_t stream) {
    const float* x      = (const float*)d_in[0];
    const void* wq      = d_in[1];
    const float* wscale = (const float*)d_in[2];
    float* y            = (float*)d_out;

    unsigned char* xq  = (unsigned char*)d_ws + XQ_OFF;
    unsigned char* wq8 = (unsigned char*)d_ws + WQ_OFF;
    float* xs          = (float*)((unsigned char*)d_ws + XS_OFF);
    int* flag          = (int*)((unsigned char*)d_ws + FL_OFF);

    prep_kernel<<<QXB + DWB, 256, 0, stream>>>(x, wq, xq, wq8, xs, flag);
    gemm_mx_kernel<<<dim3(NDIM / 128, MDIM / 128), 256, 0, stream>>>(xq, wq8, xs, wscale, y);
    check_kernel<<<64, 256, 0, stream>>>(xq, wq8, xs, wscale, y, flag);
    gemm_fb_kernel<<<dim3(NDIM / 128, MDIM / 128), 256, 0, stream>>>(xq, wq8, xs, wscale, y, flag);
}